// Round 7
// baseline (307.216 us; speedup 1.0000x reference)
//
#include <hip/hip_runtime.h>

typedef short s16x8 __attribute__((ext_vector_type(8)));
typedef float f32x4 __attribute__((ext_vector_type(4)));
typedef float f32x16 __attribute__((ext_vector_type(16)));
typedef unsigned u32x4 __attribute__((ext_vector_type(4)));

// ---------- helpers ----------

__device__ __forceinline__ unsigned short bf16bits(float f) {
  // round-to-nearest-even fp32 -> bf16 (finite inputs only)
  unsigned u = __builtin_bit_cast(unsigned, f);
  unsigned rnd = 0x7FFFu + ((u >> 16) & 1u);
  return (unsigned short)((u + rnd) >> 16);
}

__device__ __forceinline__ unsigned pk_bf16(float lo, float hi) {
  // dst[15:0]=bf16(lo), dst[31:16]=bf16(hi), RNE — one VALU op
  unsigned r;
  asm("v_cvt_pk_bf16_f32 %0, %1, %2" : "=v"(r) : "v"(lo), "v"(hi));
  return r;
}

__device__ __forceinline__ void async16(const void* g, void* l) {
  // global -> LDS direct copy, 16B per lane; LDS dest = wave-uniform base + lane*16
  __builtin_amdgcn_global_load_lds((const __attribute__((address_space(1))) void*)g,
                                   (__attribute__((address_space(3))) void*)l, 16, 0, 0);
}

__device__ __forceinline__ f32x4 mfma16(s16x8 a, s16x8 b, f32x4 c) {
  return __builtin_amdgcn_mfma_f32_16x16x32_bf16(a, b, c, 0, 0, 0);
}

__device__ __forceinline__ f32x16 mfma32(s16x8 a, s16x8 b, f32x16 c) {
  return __builtin_amdgcn_mfma_f32_32x32x16_bf16(a, b, c, 0, 0, 0);
}

// XOR-swizzled LDS tile: logical (row, col8) stored at unit row*U + (col8 ^ (row&(U-1)))
__device__ __forceinline__ s16x8 lds_frag(const unsigned short* S, int row, int c8, int U) {
  int unit = row * U + (c8 ^ (row & (U - 1)));
  return *(const s16x8*)(S + unit * 8);
}

// ---------- conversion / transpose kernels ----------

__global__ __launch_bounds__(256) void cvt_f32_bf16(const float4* __restrict__ in,
                                                    unsigned short* __restrict__ out, int n4) {
  int i = blockIdx.x * blockDim.x + threadIdx.x;
  int stride = gridDim.x * blockDim.x;
  for (; i < n4; i += stride) {
    float4 v = in[i];
    uint2 o;
    o.x = pk_bf16(v.x, v.y);
    o.y = pk_bf16(v.z, v.w);
    *(uint2*)(out + (size_t)i * 4) = o;
  }
}

// out[c][r] (bf16) = in[r][c] (fp32); R,C multiples of 32
__global__ __launch_bounds__(256) void transpose_f32_bf16(const float* __restrict__ in,
                                                          unsigned short* __restrict__ out,
                                                          int R, int C) {
  __shared__ float tile[32][33];
  int c0 = blockIdx.x * 32, r0 = blockIdx.y * 32;
  int tx = threadIdx.x, ty = threadIdx.y;  // (32, 8)
  #pragma unroll
  for (int i = 0; i < 32; i += 8)
    tile[ty + i][tx] = in[(size_t)(r0 + ty + i) * C + c0 + tx];
  __syncthreads();
  #pragma unroll
  for (int i = 0; i < 32; i += 8)
    out[(size_t)(c0 + ty + i) * R + r0 + tx] = bf16bits(tile[tx][ty + i]);
}

// V: [64 bh][2048][64] bf16 -> Vt: [64 bh][64][2048] bf16 (identity key order — r3 exact)
__global__ __launch_bounds__(256) void transpose_v(const unsigned short* __restrict__ V,
                                                   unsigned short* __restrict__ Vt) {
  __shared__ unsigned short sm[64 * 68];
  int bh = blockIdx.y, kt0 = blockIdx.x * 64;
  const unsigned short* v = V + (size_t)bh * 2048 * 64 + (size_t)kt0 * 64;  // 64x64 tile, contiguous
  unsigned short* vt = Vt + (size_t)bh * 64 * 2048;
  int t = threadIdx.x;
  #pragma unroll
  for (int i = 0; i < 4; ++i) {
    int u = i * 256 + t;        // uint2 index, 4 ushorts each
    int f = u * 4;              // flat = key*64 + d
    int k = f >> 6, d0 = f & 63;
    *(uint2*)&sm[k * 68 + d0] = *(const uint2*)&v[f];
  }
  __syncthreads();
  #pragma unroll
  for (int j = 0; j < 16; ++j) {
    int o = j * 256 + t;        // d*64 + k
    int d = o >> 6, k = o & 63;
    vt[(size_t)d * 2048 + kt0 + k] = sm[k * 68 + d];
  }
}

// ---------- GEMM: C[M,N] = A[M,K] @ Bt[N,K]^T, bf16 in, fp32 acc ----------
// r3's convoy kernel with DRAIN-robust staging (round-6 post-mortem):
// BM=128, BN=256, BK=64, 512 thr (8 waves, 2M x 4N), per-wave 64x64.
// DOUBLE-buffered LDS (96KB). Per K-tile, 2 phases, each {8 ds_read ->
// s_barrier -> setprio 16 MFMA -> s_barrier}; all 6 stage chunks of tile
// t+1 FRONT-LOADED in phase 0 (>=2 phases to land), certified by ONE
// s_waitcnt vmcnt(0) before the tile-end barrier. vmcnt(0) is immune to
// compiler-introduced vmem ops (spills) — no counted ledger to corrupt
// (the r4/r6 counted-vmcnt failure mode). Drain-style schedules are 2/2
// passing this session (r5 gemm256), counted are 2/5.
// Slot hand-off: stage(t+1) targets slot s^1 (tile t-1's); all reads of
// t-1 completed before t-1's final barrier, which precedes t's phase 0.
// Block-wide certify: each wave drains its own loads before the final
// barrier -> barrier propagates completion block-wide (round-1 race rule).
// + XCD swizzle (bijective; REQUIRES gridDim.x==32 and nwg%8==0 — both
// call sites satisfy): each XCD owns contiguous output rows -> A-panels
// stay in its private L2.

template <typename EPI>
__global__ __launch_bounds__(512, 2) void gemm8(const unsigned short* __restrict__ A,
                                                const unsigned short* __restrict__ Bt,
                                                int K, EPI epi) {
  __shared__ __align__(16) unsigned short As[2 * 128 * 64];  // 32KB, 2 slots
  __shared__ __align__(16) unsigned short Bs[2 * 256 * 64];  // 64KB, 2 slots
  const int tid = threadIdx.x, wid = tid >> 6, lane = tid & 63;
  const int quad = lane >> 4, l16 = lane & 15;
  // XCD swizzle (shift-only: gridDim.x == 32 at both call sites)
  const int bid = blockIdx.y * 32 + blockIdx.x;
  const int nwg = 32 * gridDim.y;
  const int wg = (bid & 7) * (nwg >> 3) + (bid >> 3);
  const int bm0 = (wg >> 5) * 128, bn0 = (wg & 31) * 256;
  const int wm = (wid & 1) * 64, wn = (wid >> 1) * 64;
  const int NT = K >> 6;
  f32x4 acc[4][4] = {};

  // staging (both-sides swizzle: linear LDS dest, inverse-swizzled global
  // source, swizzled ds_read — r3-proven layout)
  const int srow = tid >> 3;
  const int sc8 = (tid & 7) ^ (srow & 7);
  // chunk k of K-tile tk into slot s: k 0..1 = A rows k*64.., k 2..5 = B rows (k-2)*64..
  auto stage = [&](int s, int tk, int k) {
    int col = tk * 64 + sc8 * 8;
    if (k < 2)
      async16(A + (size_t)(bm0 + k * 64 + srow) * K + col,
              (char*)As + s * 16384 + k * 8192 + wid * 1024);
    else
      async16(Bt + (size_t)(bn0 + (k - 2) * 64 + srow) * K + col,
              (char*)Bs + s * 32768 + (k - 2) * 8192 + wid * 1024);
  };

  // prologue: tile 0 -> slot 0; drain; barrier
  #pragma unroll
  for (int k = 0; k < 6; ++k) stage(0, 0, k);
  asm volatile("s_waitcnt vmcnt(0)" ::: "memory");
  __builtin_amdgcn_s_barrier();
  __builtin_amdgcn_sched_barrier(0);

  for (int t = 0; t < NT; ++t) {
    const int s = t & 1;
    const unsigned short* as = As + s * 8192;     // elements
    const unsigned short* bs = Bs + s * 16384;    // elements
    const bool pf = (t + 1 < NT);

    // ---- phase 0: ds_read kk=0 || front-load ALL of tile t+1's staging ----
    {
      s16x8 a[4], b[4];
      #pragma unroll
      for (int i = 0; i < 4; ++i) a[i] = lds_frag(as, wm + i * 16 + l16, quad, 8);
      #pragma unroll
      for (int j = 0; j < 4; ++j) b[j] = lds_frag(bs, wn + j * 16 + l16, quad, 8);
      if (pf) {
        #pragma unroll
        for (int k = 0; k < 6; ++k) stage(s ^ 1, t + 1, k);
      }
      __builtin_amdgcn_sched_barrier(0);  // pin phase memory ops before barrier
      __builtin_amdgcn_s_barrier();       // convoy: waves enter MFMA together
      __builtin_amdgcn_s_setprio(1);
      #pragma unroll
      for (int i = 0; i < 4; ++i)
        #pragma unroll
        for (int j = 0; j < 4; ++j)
          acc[i][j] = mfma16(a[i], b[j], acc[i][j]);
      __builtin_amdgcn_s_setprio(0);
      __builtin_amdgcn_sched_barrier(0);
      __builtin_amdgcn_s_barrier();       // phase end
    }

    // ---- phase 1: ds_read kk=1; drain + certify at tile end ----
    {
      s16x8 a[4], b[4];
      #pragma unroll
      for (int i = 0; i < 4; ++i) a[i] = lds_frag(as, wm + i * 16 + l16, 4 + quad, 8);
      #pragma unroll
      for (int j = 0; j < 4; ++j) b[j] = lds_frag(bs, wn + j * 16 + l16, 4 + quad, 8);
      __builtin_amdgcn_sched_barrier(0);
      __builtin_amdgcn_s_barrier();
      __builtin_amdgcn_s_setprio(1);
      #pragma unroll
      for (int i = 0; i < 4; ++i)
        #pragma unroll
        for (int j = 0; j < 4; ++j)
          acc[i][j] = mfma16(a[i], b[j], acc[i][j]);
      __builtin_amdgcn_s_setprio(0);
      __builtin_amdgcn_sched_barrier(0);
      asm volatile("s_waitcnt vmcnt(0)" ::: "memory");  // drain: t+1 landed (issued ~2 phases ago)
      __builtin_amdgcn_s_barrier();       // block-wide certify; slot s free for t+2
      __builtin_amdgcn_sched_barrier(0);
    }
  }

  // epilogue: per (i,j) one call, 4 consecutive m per lane
  #pragma unroll
  for (int i = 0; i < 4; ++i)
    #pragma unroll
    for (int j = 0; j < 4; ++j)
      epi.store4(bm0 + wm + i * 16 + quad * 4, bn0 + wn + j * 16 + l16, acc[i][j]);
}

// QKV (swapped orientation): m = qkv-dim (s*1024 + h*64 + d), n = x-row (b*2048+ns).
// 4 consecutive m = 4 consecutive d -> one 8B store into [bh][ns][64] layout.
struct QKVEpi {
  unsigned short *Q, *K, *V;  // each [64 bh][2048 ns][64 d]
  float qscale;               // hd^-0.5 * log2(e): folds softmax into exp2 domain
  __device__ __forceinline__ void store4(int m0, int n, f32x4 v) const {
    int s = m0 >> 10, h = (m0 >> 6) & 15, d = m0 & 63;
    int b = n >> 11, ns = n & 2047;
    unsigned short* dst = (s == 0) ? Q : ((s == 1) ? K : V);
    float sc = (s == 0) ? qscale : 1.f;
    uint2 o;
    o.x = pk_bf16(v[0] * sc, v[1] * sc);
    o.y = pk_bf16(v[2] * sc, v[3] * sc);
    *(uint2*)&dst[(((size_t)b * 16 + h) * 2048 + ns) * 64 + d] = o;
  }
};

// Proj (swapped orientation): m = out-col, n = x-row. One float4 store + float4 bias.
struct ProjEpi {
  const float* bias;
  float* out;
  __device__ __forceinline__ void store4(int m0, int n, f32x4 v) const {
    float4 b4 = *(const float4*)&bias[m0];
    float4 o = {v[0] + b4.x, v[1] + b4.y, v[2] + b4.z, v[3] + b4.w};
    *(float4*)&out[(size_t)n * 1024 + m0] = o;
  }
};

// ---------- flash attention ----------
// (r3-exact, 3x-passed, untouched this round)
// S^T form, register-resident P, max-free softmax, double-buffered staging
// (one barrier per tile), 32 q-rows per wave, fragment-major LDS staging
// (zero bank conflicts). P B-frag via half-swap dword shuffle (known-good).
// XCD-aware block swizzle; T5 setprio around MFMA clusters.
// Q,K: [64 bh][2048][64] bf16 (Q pre-scaled by hd^-0.5*log2e);  Vt: [64 bh][64][2048]
// O: [4][2048][16][64] bf16.
__global__ __launch_bounds__(256, 4) void flash_attn(const unsigned short* __restrict__ Q,
                                                     const unsigned short* __restrict__ K,
                                                     const unsigned short* __restrict__ Vt,
                                                     unsigned short* __restrict__ O) {
  __shared__ __align__(16) unsigned short Ks[2][8 * 512];  // dbuf, 8 chunks (kf,s) of 64 frags
  __shared__ __align__(16) unsigned short Vs[2][8 * 512];  // dbuf, 8 chunks (ktstep,f)
  const int tid = threadIdx.x, wid = tid >> 6, lane = tid & 63;
  const int l31 = lane & 31, half = lane >> 5;
  // XCD swizzle: bijection bid -> (bh, qt); all blocks of a bh share bid&7
  const int bid = blockIdx.y * gridDim.x + blockIdx.x;  // 0..1023
  const int xcd = bid & 7, idx = bid >> 3;
  const int bh = xcd * 8 + (idx & 7);
  const int qt = idx >> 3;
  const unsigned short* Qg = Q + (size_t)bh * 2048 * 64;
  const unsigned short* Kg = K + (size_t)bh * 2048 * 64;
  const unsigned short* Vg = Vt + (size_t)bh * 64 * 2048;
  const int qrow = qt * 128 + wid * 32 + l31;  // this lane's q-row

  // Q as B-operand fragments: B[k=d][n=qrow]; lane holds d = s*16 + half*8 + j
  s16x8 qB[4];
  #pragma unroll
  for (int s = 0; s < 4; ++s)
    qB[s] = *(const s16x8*)&Qg[(size_t)qrow * 64 + s * 16 + half * 8];

  // staging: waves 0,1 stage K chunks 0..7 (kf=c>>2, s=c&3); waves 2,3 stage V
  // chunks 0..7 (ktstep=c>>1, f=c&1). Lane fetches exactly its fragment source.
  const bool isK = wid < 2;
  int sA[4];
  #pragma unroll
  for (int t = 0; t < 4; ++t) {
    int c = (wid & 1) * 4 + t;
    if (isK) sA[t] = ((c >> 2) * 32 + l31) * 64 + ((c & 3) * 2 + half) * 8;
    else     sA[t] = ((c & 1) * 32 + l31) * 2048 + (c >> 1) * 16 + half * 8;
  }

  auto stage = [&](int kt, int buf) {
    const int kb = kt * 64;
    #pragma unroll
    for (int t = 0; t < 4; ++t) {
      int c = (wid & 1) * 4 + t;
      if (isK) async16(Kg + (size_t)kb * 64 + sA[t], (char*)&Ks[buf][0] + c * 1024);
      else     async16(Vg + kb + sA[t],              (char*)&Vs[buf][0] + c * 1024);
    }
  };

  f32x16 oacc[2] = {};  // [f]: O^T[d = f*32 + (r&3)+8*(r>>2)+4*half][qrow]
  float l_i = 0.f;
  const f32x16 fz = {};

  stage(0, 0);
  for (int kt = 0; kt < 32; ++kt) {
    const int cur = kt & 1;
    __syncthreads();  // tile kt visible to all; buf cur^1 free (all done with kt-1)
    if (kt + 1 < 32) stage(kt + 1, cur ^ 1);  // in flight across this tile's compute
    const unsigned short* ks = &Ks[cur][0];
    const unsigned short* vs = &Vs[cur][0];

    #pragma unroll
    for (int kf = 0; kf < 2; ++kf) {  // 32-key chunk: QK -> softmax -> PV
      // S^T = K @ Q^T; A-frag: keys kf*32 + (r&3)+8*(r>>2)+4*half, col = qrow
      f32x16 st;
      __builtin_amdgcn_s_setprio(1);
      {
        s16x8 a = *(const s16x8*)&ks[((kf * 4 + 0) * 64 + lane) * 8];
        st = mfma32(a, qB[0], fz);
      }
      #pragma unroll
      for (int s = 1; s < 4; ++s) {
        s16x8 a = *(const s16x8*)&ks[((kf * 4 + s) * 64 + lane) * 8];
        st = mfma32(a, qB[s], st);
      }
      __builtin_amdgcn_s_setprio(0);
      // max-free softmax (scores bounded; fp32 can't overflow), tree-reduced sum
      float a0 = 0.f, a1 = 0.f, a2 = 0.f, a3 = 0.f;
      #pragma unroll
      for (int r = 0; r < 16; r += 4) {
        float p0 = __builtin_amdgcn_exp2f(st[r + 0]);
        float p1 = __builtin_amdgcn_exp2f(st[r + 1]);
        float p2 = __builtin_amdgcn_exp2f(st[r + 2]);
        float p3 = __builtin_amdgcn_exp2f(st[r + 3]);
        st[r + 0] = p0; st[r + 1] = p1; st[r + 2] = p2; st[r + 3] = p3;
        a0 += p0; a1 += p1; a2 += p2; a3 += p3;
      }
      float rs = (a0 + a1) + (a2 + a3);
      rs += __shfl_xor(rs, 32);
      l_i += rs;
      // pack P to bf16 B-frags (half-swap via dword shuffle) + PV
      #pragma unroll
      for (int t = 0; t < 2; ++t) {  // 16-key step within chunk
        int rb = t * 8;
        unsigned pa0 = pk_bf16(st[rb + 0], st[rb + 1]);
        unsigned pa1 = pk_bf16(st[rb + 2], st[rb + 3]);
        unsigned pb0 = pk_bf16(st[rb + 4], st[rb + 5]);
        unsigned pb1 = pk_bf16(st[rb + 6], st[rb + 7]);
        unsigned s0 = half ? pa0 : pb0;
        unsigned s1 = half ? pa1 : pb1;
        unsigned r0 = (unsigned)__shfl_xor((int)s0, 32);
        unsigned r1 = (unsigned)__shfl_xor((int)s1, 32);
        u32x4 bP;
        bP[0] = half ? r0 : pa0;  // B-frag keys kf*32 + t*16 + half*8 + {0..7}
        bP[1] = half ? r1 : pa1;
        bP[2] = half ? pb0 : r0;
        bP[3] = half ? pb1 : r1;
        __builtin_amdgcn_s_setprio(1);
        #pragma unroll
        for (int f = 0; f < 2; ++f) {
          s16x8 aV = *(const s16x8*)&vs[(((kf * 2 + t) * 2 + f) * 64 + lane) * 8];
          oacc[f] = mfma32(aV, __builtin_bit_cast(s16x8, bP), oacc[f]);
        }
        __builtin_amdgcn_s_setprio(0);
      }
    }
  }

  // epilogue: O^T D-layout -> O[b][ns][h][d]; regs q*4..q*4+3 are d contiguous
  const int b = bh >> 4, h = bh & 15;
  float inv = 1.f / l_i;
  size_t base = (((size_t)b * 2048 + qrow) * 16 + h) * 64;
  #pragma unroll
  for (int f = 0; f < 2; ++f)
    #pragma unroll
    for (int q = 0; q < 4; ++q) {
      int d0 = f * 32 + q * 8 + half * 4;
      uint2 o;
      o.x = pk_bf16(oacc[f][q * 4 + 0] * inv, oacc[f][q * 4 + 1] * inv);
      o.y = pk_bf16(oacc[f][q * 4 + 2] * inv, oacc[f][q * 4 + 3] * inv);
      *(uint2*)&O[base + d0] = o;
    }
}

// ---------- launch ----------

extern "C" void kernel_launch(void* const* d_in, const int* in_sizes, int n_in,
                              void* d_out, int out_size, void* d_ws, size_t ws_size,
                              hipStream_t stream) {
  (void)in_sizes; (void)n_in; (void)out_size; (void)ws_size;
  const float* x = (const float*)d_in[0];       // [4,2048,1024]
  const float* w_qkv = (const float*)d_in[1];   // [1024,3072]
  const float* w_proj = (const float*)d_in[2];  // [1024,1024]
  const float* b_proj = (const float*)d_in[3];  // [1024]
  float* out = (float*)d_out;
  char* ws = (char*)d_ws;
  const size_t MB = 1ull << 20;
  unsigned short* Xb  = (unsigned short*)(ws);            // 16MB (reused as Vt after QKV GEMM)
  unsigned short* Wqt = (unsigned short*)(ws + 16 * MB);  // 6MB  [3072][1024]
  unsigned short* Wpt = (unsigned short*)(ws + 22 * MB);  // 2MB  [1024][1024]
  unsigned short* Qb  = (unsigned short*)(ws + 24 * MB);  // 16MB [64 bh][2048][64]
  unsigned short* Kb  = (unsigned short*)(ws + 40 * MB);  // 16MB
  unsigned short* Vb  = (unsigned short*)(ws + 56 * MB);  // 16MB (reused as O after transpose_v)
  unsigned short* Vt  = Xb;  // Xb free after QKV GEMM
  unsigned short* Ob  = Vb;  // Vb free after transpose_v

  cvt_f32_bf16<<<2048, 256, 0, stream>>>((const float4*)x, Xb, 8388608 / 4);
  transpose_f32_bf16<<<dim3(96, 32), dim3(32, 8), 0, stream>>>(w_qkv, Wqt, 1024, 3072);
  transpose_f32_bf16<<<dim3(32, 32), dim3(32, 8), 0, stream>>>(w_proj, Wpt, 1024, 1024);

  // swapped orientation: A = weights (M=3072), Bt = X (N=8192); 32x24=768 blocks = 3 exact rounds
  QKVEpi e1{Qb, Kb, Vb, 0.125f * 1.44269504088896340736f};
  gemm8<QKVEpi><<<dim3(32, 24), 512, 0, stream>>>(Wqt, Xb, 1024, e1);

  transpose_v<<<dim3(32, 64), 256, 0, stream>>>(Vb, Vt);
  flash_attn<<<dim3(16, 64), 256, 0, stream>>>(Qb, Kb, Vt, Ob);

  // swapped orientation: A = W_proj^T (M=1024), Bt = attention output (N=8192); 256 blocks = 1 round
  ProjEpi e2{b_proj, out};
  gemm8<ProjEpi><<<dim3(32, 8), 512, 0, stream>>>(Wpt, Ob, 1024, e2);
}

// Round 9
// 280.387 us; speedup vs baseline: 1.0957x; 1.0957x over previous
//
#include <hip/hip_runtime.h>

typedef short s16x8 __attribute__((ext_vector_type(8)));
typedef float f32x4 __attribute__((ext_vector_type(4)));
typedef float f32x16 __attribute__((ext_vector_type(16)));
typedef unsigned u32x4 __attribute__((ext_vector_type(4)));

// ---------- helpers ----------

__device__ __forceinline__ unsigned short bf16bits(float f) {
  // round-to-nearest-even fp32 -> bf16 (finite inputs only)
  unsigned u = __builtin_bit_cast(unsigned, f);
  unsigned rnd = 0x7FFFu + ((u >> 16) & 1u);
  return (unsigned short)((u + rnd) >> 16);
}

__device__ __forceinline__ unsigned pk_bf16(float lo, float hi) {
  // dst[15:0]=bf16(lo), dst[31:16]=bf16(hi), RNE — one VALU op
  unsigned r;
  asm("v_cvt_pk_bf16_f32 %0, %1, %2" : "=v"(r) : "v"(lo), "v"(hi));
  return r;
}

__device__ __forceinline__ void async16(const void* g, void* l) {
  // global -> LDS direct copy, 16B per lane; LDS dest = wave-uniform base + lane*16
  __builtin_amdgcn_global_load_lds((const __attribute__((address_space(1))) void*)g,
                                   (__attribute__((address_space(3))) void*)l, 16, 0, 0);
}

__device__ __forceinline__ f32x4 mfma16(s16x8 a, s16x8 b, f32x4 c) {
  return __builtin_amdgcn_mfma_f32_16x16x32_bf16(a, b, c, 0, 0, 0);
}

__device__ __forceinline__ f32x16 mfma32(s16x8 a, s16x8 b, f32x16 c) {
  return __builtin_amdgcn_mfma_f32_32x32x16_bf16(a, b, c, 0, 0, 0);
}

// XOR-swizzled LDS tile: logical (row, col8) stored at unit row*U + (col8 ^ (row&(U-1)))
__device__ __forceinline__ s16x8 lds_frag(const unsigned short* S, int row, int c8, int U) {
  int unit = row * U + (c8 ^ (row & (U - 1)));
  return *(const s16x8*)(S + unit * 8);
}

// ---------- fused preprocessing: cvt x->bf16 + both weight transposes ----------
// THE ONLY CHANGE vs the 276.7-us r3-passing build. One launch replaces three
// (independent, all HBM-bound; overlap + 2 fewer launch gaps). Bodies are the
// proven kernels verbatim; only the block-index mapping differs (desk-checked
// bijective coverage of the original grids).
// blocks [0,2048): cvt; [2048,5120): w_qkv transpose (96x32); [5120,6144): w_proj (32x32).
__global__ __launch_bounds__(256) void prep(const float4* __restrict__ x4,
                                            unsigned short* __restrict__ Xb,
                                            const float* __restrict__ w_qkv,
                                            unsigned short* __restrict__ Wqt,
                                            const float* __restrict__ w_proj,
                                            unsigned short* __restrict__ Wpt) {
  __shared__ float tile[32][33];
  const int blk = blockIdx.x, t = threadIdx.x;
  if (blk < 2048) {
    // cvt_f32_bf16 body (grid-stride identical to the proven 2048x256 launch)
    const int n4 = 8388608 / 4, stride = 2048 * 256;
    for (int i = blk * 256 + t; i < n4; i += stride) {
      float4 v = x4[i];
      uint2 o;
      o.x = pk_bf16(v.x, v.y);
      o.y = pk_bf16(v.z, v.w);
      *(uint2*)(Xb + (size_t)i * 4) = o;
    }
    return;
  }
  // transpose_f32_bf16 body; thread (32,8) -> tx=t&31, ty=t>>5
  const float* in;
  unsigned short* out;
  int R, C, c0, r0;
  if (blk < 2048 + 3072) {
    int idx = blk - 2048;              // original grid (96, 32)
    in = w_qkv; out = Wqt; R = 1024; C = 3072;
    c0 = (idx % 96) * 32; r0 = (idx / 96) * 32;
  } else {
    int idx = blk - (2048 + 3072);     // original grid (32, 32)
    in = w_proj; out = Wpt; R = 1024; C = 1024;
    c0 = (idx & 31) * 32; r0 = (idx >> 5) * 32;
  }
  const int tx = t & 31, ty = t >> 5;
  #pragma unroll
  for (int i = 0; i < 32; i += 8)
    tile[ty + i][tx] = in[(size_t)(r0 + ty + i) * C + c0 + tx];
  __syncthreads();
  #pragma unroll
  for (int i = 0; i < 32; i += 8)
    out[(size_t)(c0 + ty + i) * R + r0 + tx] = bf16bits(tile[tx][ty + i]);
}

// V: [64 bh][2048][64] bf16 -> Vt: [64 bh][64][2048] bf16 (identity key order — r3 exact)
__global__ __launch_bounds__(256) void transpose_v(const unsigned short* __restrict__ V,
                                                   unsigned short* __restrict__ Vt) {
  __shared__ unsigned short sm[64 * 68];
  int bh = blockIdx.y, kt0 = blockIdx.x * 64;
  const unsigned short* v = V + (size_t)bh * 2048 * 64 + (size_t)kt0 * 64;  // 64x64 tile, contiguous
  unsigned short* vt = Vt + (size_t)bh * 64 * 2048;
  int t = threadIdx.x;
  #pragma unroll
  for (int i = 0; i < 4; ++i) {
    int u = i * 256 + t;        // uint2 index, 4 ushorts each
    int f = u * 4;              // flat = key*64 + d
    int k = f >> 6, d0 = f & 63;
    *(uint2*)&sm[k * 68 + d0] = *(const uint2*)&v[f];
  }
  __syncthreads();
  #pragma unroll
  for (int j = 0; j < 16; ++j) {
    int o = j * 256 + t;        // d*64 + k
    int d = o >> 6, k = o & 63;
    vt[(size_t)d * 2048 + kt0 + k] = sm[k * 68 + d];
  }
}

// ---------- GEMM: C[M,N] = A[M,K] @ Bt[N,K]^T, bf16 in, fp32 acc ----------
// r3-EXACT per-phase convoy schedule (best passing config, 276.7 us; passed
// r2/r3; r6/r8 "failures" of counted schedules are now fingerprint-attributed
// to broken flash P-paths, not this ledger):
// BM=128, BN=256, BK=64, 512 thr (8 waves, 2M x 4N), per-wave 64x64.
// Triple-buffered LDS (144KB, 1 blk/CU). Per K-tile: 2 phases, each = {8
// ds_read (one kstep's a[4]+b[4]) || 3 global_load_lds chunks of tile t+2 ->
// s_barrier -> setprio(1) 16 MFMA setprio(0) -> s_barrier}. One counted
// s_waitcnt vmcnt(6) per tile, after the ph2 MFMA cluster.
//
// vmcnt ledger (6 loads/thread/tile, in-order retirement):
//   issue: ... (t-1).ph1:3 + (t-1).ph2:3 [tile t+1] | t.ph1:3 + t.ph2:3 [t+2]
//   at t.ph2 end: vmcnt(6) retires tile t+1 fully, leaves tile t+2's 6.
//   Per-wave count + 2 barriers before tile t+1's first ds_read = block-wide
//   certification (round-1 race rule). Prologue: 12 loads, vmcnt(6), barrier.
//   Tail: t+2>=NT -> vmcnt(0).

template <typename EPI>
__global__ __launch_bounds__(512, 2) void gemm8(const unsigned short* __restrict__ A,
                                                const unsigned short* __restrict__ Bt,
                                                int K, EPI epi) {
  __shared__ __align__(16) unsigned short As[3 * 128 * 64];  // 48KB, 3 slots
  __shared__ __align__(16) unsigned short Bs[3 * 256 * 64];  // 96KB, 3 slots
  const int tid = threadIdx.x, wid = tid >> 6, lane = tid & 63;
  const int quad = lane >> 4, l16 = lane & 15;
  const int bm0 = blockIdx.y * 128, bn0 = blockIdx.x * 256;
  const int wm = (wid & 1) * 64, wn = (wid >> 1) * 64;
  const int NT = K >> 6;
  f32x4 acc[4][4] = {};

  // staging (both-sides swizzle: linear LDS dest, inverse-swizzled global
  // source, swizzled ds_read — proven layout)
  const int srow = tid >> 3;
  const int sc8 = (tid & 7) ^ (srow & 7);
  // chunk k of K-tile tk into slot s: k 0..1 = A rows k*64.., k 2..5 = B rows (k-2)*64..
  auto stage = [&](int s, int tk, int k) {
    int col = tk * 64 + sc8 * 8;
    if (k < 2)
      async16(A + (size_t)(bm0 + k * 64 + srow) * K + col,
              (char*)As + s * 16384 + k * 8192 + wid * 1024);
    else
      async16(Bt + (size_t)(bn0 + (k - 2) * 64 + srow) * K + col,
              (char*)Bs + s * 32768 + (k - 2) * 8192 + wid * 1024);
  };

  // prologue: tiles 0 and 1 staged (12 loads); certify tile 0 block-wide
  #pragma unroll
  for (int k = 0; k < 6; ++k) stage(0, 0, k);
  #pragma unroll
  for (int k = 0; k < 6; ++k) stage(1, 1, k);
  asm volatile("s_waitcnt vmcnt(6)" ::: "memory");
  __builtin_amdgcn_s_barrier();
  __builtin_amdgcn_sched_barrier(0);

  int sc = 0;  // slot of tile t
  for (int t = 0; t < NT; ++t) {
    const unsigned short* as = As + sc * 8192;    // elements
    const unsigned short* bs = Bs + sc * 16384;   // elements
    const int sp = (sc == 0) ? 2 : sc - 1;        // slot (t+2)%3
    const bool pf = (t + 2 < NT);

    #pragma unroll
    for (int kk = 0; kk < 2; ++kk) {
      // phase body: ds_reads of this kstep + 3 staging chunks, then convoy
      s16x8 a[4], b[4];
      #pragma unroll
      for (int i = 0; i < 4; ++i) a[i] = lds_frag(as, wm + i * 16 + l16, kk * 4 + quad, 8);
      #pragma unroll
      for (int j = 0; j < 4; ++j) b[j] = lds_frag(bs, wn + j * 16 + l16, kk * 4 + quad, 8);
      if (pf) { stage(sp, t + 2, kk * 3 + 0); stage(sp, t + 2, kk * 3 + 1); stage(sp, t + 2, kk * 3 + 2); }
      __builtin_amdgcn_sched_barrier(0);  // pin phase memory ops before barrier
      __builtin_amdgcn_s_barrier();       // convoy: waves enter MFMA together
      __builtin_amdgcn_s_setprio(1);
      #pragma unroll
      for (int i = 0; i < 4; ++i)
        #pragma unroll
        for (int j = 0; j < 4; ++j)
          acc[i][j] = mfma16(a[i], b[j], acc[i][j]);
      __builtin_amdgcn_s_setprio(0);
      __builtin_amdgcn_sched_barrier(0);  // keep MFMA cluster inside the phase
      if (kk == 1) {                      // certify tile t+1 (counted, after MFMA)
        if (pf) asm volatile("s_waitcnt vmcnt(6)" ::: "memory");
        else    asm volatile("s_waitcnt vmcnt(0)" ::: "memory");
      }
      __builtin_amdgcn_s_barrier();       // phase end
    }
    sc = (sc == 2) ? 0 : sc + 1;
  }

  // epilogue: per (i,j) one call, 4 consecutive m per lane
  #pragma unroll
  for (int i = 0; i < 4; ++i)
    #pragma unroll
    for (int j = 0; j < 4; ++j)
      epi.store4(bm0 + wm + i * 16 + quad * 4, bn0 + wn + j * 16 + l16, acc[i][j]);
}

// QKV (swapped orientation): m = qkv-dim (s*1024 + h*64 + d), n = x-row (b*2048+ns).
// 4 consecutive m = 4 consecutive d -> one 8B store into [bh][ns][64] layout.
struct QKVEpi {
  unsigned short *Q, *K, *V;  // each [64 bh][2048 ns][64 d]
  float qscale;               // hd^-0.5 * log2(e): folds softmax into exp2 domain
  __device__ __forceinline__ void store4(int m0, int n, f32x4 v) const {
    int s = m0 >> 10, h = (m0 >> 6) & 15, d = m0 & 63;
    int b = n >> 11, ns = n & 2047;
    unsigned short* dst = (s == 0) ? Q : ((s == 1) ? K : V);
    float sc = (s == 0) ? qscale : 1.f;
    uint2 o;
    o.x = pk_bf16(v[0] * sc, v[1] * sc);
    o.y = pk_bf16(v[2] * sc, v[3] * sc);
    *(uint2*)&dst[(((size_t)b * 16 + h) * 2048 + ns) * 64 + d] = o;
  }
};

// Proj (swapped orientation): m = out-col, n = x-row. One float4 store + float4 bias.
struct ProjEpi {
  const float* bias;
  float* out;
  __device__ __forceinline__ void store4(int m0, int n, f32x4 v) const {
    float4 b4 = *(const float4*)&bias[m0];
    float4 o = {v[0] + b4.x, v[1] + b4.y, v[2] + b4.z, v[3] + b4.w};
    *(float4*)&out[(size_t)n * 1024 + m0] = o;
  }
};

// ---------- flash attention ----------
// r3-EXACT shuffle version (5/5 passing across r0/r2/r3/r5/r7 — UNTOUCHED).
// S^T form, register-resident P, max-free softmax, double-buffered staging
// (one barrier per tile), 32 q-rows per wave, fragment-major LDS staging
// (zero bank conflicts). P B-frag via half-swap dword shuffle (known-good).
// XCD-aware block swizzle; T5 setprio around MFMA clusters.
// NOTE for future rounds: the correct permlane32_swap drop-in (pinned by the
// r4/r8 failure fingerprint; HW semantic is vdst.lo<->vsrc.hi) is:
//   w0 = __builtin_amdgcn_permlane32_swap(pb0, pa0, false, false);
//   bP[0] = w0[1]; bP[2] = w0[0];   (and likewise w1 = swap(pb1, pa1))
// — single-change candidate, NOT bundled here.
// Q,K: [64 bh][2048][64] bf16 (Q pre-scaled by hd^-0.5*log2e);  Vt: [64 bh][64][2048]
// O: [4][2048][16][64] bf16.
__global__ __launch_bounds__(256, 4) void flash_attn(const unsigned short* __restrict__ Q,
                                                     const unsigned short* __restrict__ K,
                                                     const unsigned short* __restrict__ Vt,
                                                     unsigned short* __restrict__ O) {
  __shared__ __align__(16) unsigned short Ks[2][8 * 512];  // dbuf, 8 chunks (kf,s) of 64 frags
  __shared__ __align__(16) unsigned short Vs[2][8 * 512];  // dbuf, 8 chunks (ktstep,f)
  const int tid = threadIdx.x, wid = tid >> 6, lane = tid & 63;
  const int l31 = lane & 31, half = lane >> 5;
  // XCD swizzle: bijection bid -> (bh, qt); all blocks of a bh share bid&7
  const int bid = blockIdx.y * gridDim.x + blockIdx.x;  // 0..1023
  const int xcd = bid & 7, idx = bid >> 3;
  const int bh = xcd * 8 + (idx & 7);
  const int qt = idx >> 3;
  const unsigned short* Qg = Q + (size_t)bh * 2048 * 64;
  const unsigned short* Kg = K + (size_t)bh * 2048 * 64;
  const unsigned short* Vg = Vt + (size_t)bh * 64 * 2048;
  const int qrow = qt * 128 + wid * 32 + l31;  // this lane's q-row

  // Q as B-operand fragments: B[k=d][n=qrow]; lane holds d = s*16 + half*8 + j
  s16x8 qB[4];
  #pragma unroll
  for (int s = 0; s < 4; ++s)
    qB[s] = *(const s16x8*)&Qg[(size_t)qrow * 64 + s * 16 + half * 8];

  // staging: waves 0,1 stage K chunks 0..7 (kf=c>>2, s=c&3); waves 2,3 stage V
  // chunks 0..7 (ktstep=c>>1, f=c&1). Lane fetches exactly its fragment source.
  const bool isK = wid < 2;
  int sA[4];
  #pragma unroll
  for (int t = 0; t < 4; ++t) {
    int c = (wid & 1) * 4 + t;
    if (isK) sA[t] = ((c >> 2) * 32 + l31) * 64 + ((c & 3) * 2 + half) * 8;
    else     sA[t] = ((c & 1) * 32 + l31) * 2048 + (c >> 1) * 16 + half * 8;
  }

  auto stage = [&](int kt, int buf) {
    const int kb = kt * 64;
    #pragma unroll
    for (int t = 0; t < 4; ++t) {
      int c = (wid & 1) * 4 + t;
      if (isK) async16(Kg + (size_t)kb * 64 + sA[t], (char*)&Ks[buf][0] + c * 1024);
      else     async16(Vg + kb + sA[t],              (char*)&Vs[buf][0] + c * 1024);
    }
  };

  f32x16 oacc[2] = {};  // [f]: O^T[d = f*32 + (r&3)+8*(r>>2)+4*half][qrow]
  float l_i = 0.f;
  const f32x16 fz = {};

  stage(0, 0);
  for (int kt = 0; kt < 32; ++kt) {
    const int cur = kt & 1;
    __syncthreads();  // tile kt visible to all; buf cur^1 free (all done with kt-1)
    if (kt + 1 < 32) stage(kt + 1, cur ^ 1);  // in flight across this tile's compute
    const unsigned short* ks = &Ks[cur][0];
    const unsigned short* vs = &Vs[cur][0];

    #pragma unroll
    for (int kf = 0; kf < 2; ++kf) {  // 32-key chunk: QK -> softmax -> PV
      // S^T = K @ Q^T; A-frag: keys kf*32 + (r&3)+8*(r>>2)+4*half, col = qrow
      f32x16 st;
      __builtin_amdgcn_s_setprio(1);
      {
        s16x8 a = *(const s16x8*)&ks[((kf * 4 + 0) * 64 + lane) * 8];
        st = mfma32(a, qB[0], fz);
      }
      #pragma unroll
      for (int s = 1; s < 4; ++s) {
        s16x8 a = *(const s16x8*)&ks[((kf * 4 + s) * 64 + lane) * 8];
        st = mfma32(a, qB[s], st);
      }
      __builtin_amdgcn_s_setprio(0);
      // max-free softmax (scores bounded; fp32 can't overflow), tree-reduced sum
      float a0 = 0.f, a1 = 0.f, a2 = 0.f, a3 = 0.f;
      #pragma unroll
      for (int r = 0; r < 16; r += 4) {
        float p0 = __builtin_amdgcn_exp2f(st[r + 0]);
        float p1 = __builtin_amdgcn_exp2f(st[r + 1]);
        float p2 = __builtin_amdgcn_exp2f(st[r + 2]);
        float p3 = __builtin_amdgcn_exp2f(st[r + 3]);
        st[r + 0] = p0; st[r + 1] = p1; st[r + 2] = p2; st[r + 3] = p3;
        a0 += p0; a1 += p1; a2 += p2; a3 += p3;
      }
      float rs = (a0 + a1) + (a2 + a3);
      rs += __shfl_xor(rs, 32);
      l_i += rs;
      // pack P to bf16 B-frags (half-swap via dword shuffle) + PV
      #pragma unroll
      for (int t = 0; t < 2; ++t) {  // 16-key step within chunk
        int rb = t * 8;
        unsigned pa0 = pk_bf16(st[rb + 0], st[rb + 1]);
        unsigned pa1 = pk_bf16(st[rb + 2], st[rb + 3]);
        unsigned pb0 = pk_bf16(st[rb + 4], st[rb + 5]);
        unsigned pb1 = pk_bf16(st[rb + 6], st[rb + 7]);
        unsigned s0 = half ? pa0 : pb0;
        unsigned s1 = half ? pa1 : pb1;
        unsigned r0 = (unsigned)__shfl_xor((int)s0, 32);
        unsigned r1 = (unsigned)__shfl_xor((int)s1, 32);
        u32x4 bP;
        bP[0] = half ? r0 : pa0;  // B-frag keys kf*32 + t*16 + half*8 + {0..7}
        bP[1] = half ? r1 : pa1;
        bP[2] = half ? pb0 : r0;
        bP[3] = half ? pb1 : r1;
        __builtin_amdgcn_s_setprio(1);
        #pragma unroll
        for (int f = 0; f < 2; ++f) {
          s16x8 aV = *(const s16x8*)&vs[(((kf * 2 + t) * 2 + f) * 64 + lane) * 8];
          oacc[f] = mfma32(aV, __builtin_bit_cast(s16x8, bP), oacc[f]);
        }
        __builtin_amdgcn_s_setprio(0);
      }
    }
  }

  // epilogue: O^T D-layout -> O[b][ns][h][d]; regs q*4..q*4+3 are d contiguous
  const int b = bh >> 4, h = bh & 15;
  float inv = 1.f / l_i;
  size_t base = (((size_t)b * 2048 + qrow) * 16 + h) * 64;
  #pragma unroll
  for (int f = 0; f < 2; ++f)
    #pragma unroll
    for (int q = 0; q < 4; ++q) {
      int d0 = f * 32 + q * 8 + half * 4;
      uint2 o;
      o.x = pk_bf16(oacc[f][q * 4 + 0] * inv, oacc[f][q * 4 + 1] * inv);
      o.y = pk_bf16(oacc[f][q * 4 + 2] * inv, oacc[f][q * 4 + 3] * inv);
      *(uint2*)&O[base + d0] = o;
    }
}

// ---------- launch ----------

extern "C" void kernel_launch(void* const* d_in, const int* in_sizes, int n_in,
                              void* d_out, int out_size, void* d_ws, size_t ws_size,
                              hipStream_t stream) {
  (void)in_sizes; (void)n_in; (void)out_size; (void)ws_size;
  const float* x = (const float*)d_in[0];       // [4,2048,1024]
  const float* w_qkv = (const float*)d_in[1];   // [1024,3072]
  const float* w_proj = (const float*)d_in[2];  // [1024,1024]
  const float* b_proj = (const float*)d_in[3];  // [1024]
  float* out = (float*)d_out;
  char* ws = (char*)d_ws;
  const size_t MB = 1ull << 20;
  unsigned short* Xb  = (unsigned short*)(ws);            // 16MB (reused as Vt after QKV GEMM)
  unsigned short* Wqt = (unsigned short*)(ws + 16 * MB);  // 6MB  [3072][1024]
  unsigned short* Wpt = (unsigned short*)(ws + 22 * MB);  // 2MB  [1024][1024]
  unsigned short* Qb  = (unsigned short*)(ws + 24 * MB);  // 16MB [64 bh][2048][64]
  unsigned short* Kb  = (unsigned short*)(ws + 40 * MB);  // 16MB
  unsigned short* Vb  = (unsigned short*)(ws + 56 * MB);  // 16MB (reused as O after transpose_v)
  unsigned short* Vt  = Xb;  // Xb free after QKV GEMM
  unsigned short* Ob  = Vb;  // Vb free after transpose_v

  // fused: cvt + w_qkv transpose + w_proj transpose (one launch, 3 block ranges)
  prep<<<2048 + 3072 + 1024, 256, 0, stream>>>((const float4*)x, Xb, w_qkv, Wqt, w_proj, Wpt);

  // swapped orientation: A = weights (M=3072), Bt = X (N=8192); 32x24=768 blocks = 3 exact rounds
  QKVEpi e1{Qb, Kb, Vb, 0.125f * 1.44269504088896340736f};
  gemm8<QKVEpi><<<dim3(32, 24), 512, 0, stream>>>(Wqt, Xb, 1024, e1);

  transpose_v<<<dim3(32, 64), 256, 0, stream>>>(Vb, Vt);
  flash_attn<<<dim3(16, 64), 256, 0, stream>>>(Qb, Kb, Vt, Ob);

  // swapped orientation: A = W_proj^T (M=1024), Bt = attention output (N=8192); 256 blocks = 1 round
  ProjEpi e2{b_proj, out};
  gemm8<ProjEpi><<<dim3(32, 8), 512, 0, stream>>>(Wpt, Ob, 1024, e2);
}

// Round 10
// 278.726 us; speedup vs baseline: 1.1022x; 1.0060x over previous
//
#include <hip/hip_runtime.h>

typedef short s16x8 __attribute__((ext_vector_type(8)));
typedef float f32x4 __attribute__((ext_vector_type(4)));
typedef float f32x16 __attribute__((ext_vector_type(16)));
typedef unsigned u32x4 __attribute__((ext_vector_type(4)));

// ---------- helpers ----------

__device__ __forceinline__ unsigned short bf16bits(float f) {
  // round-to-nearest-even fp32 -> bf16 (finite inputs only)
  unsigned u = __builtin_bit_cast(unsigned, f);
  unsigned rnd = 0x7FFFu + ((u >> 16) & 1u);
  return (unsigned short)((u + rnd) >> 16);
}

__device__ __forceinline__ unsigned pk_bf16(float lo, float hi) {
  // dst[15:0]=bf16(lo), dst[31:16]=bf16(hi), RNE — one VALU op
  unsigned r;
  asm("v_cvt_pk_bf16_f32 %0, %1, %2" : "=v"(r) : "v"(lo), "v"(hi));
  return r;
}

__device__ __forceinline__ void async16(const void* g, void* l) {
  // global -> LDS direct copy, 16B per lane; LDS dest = wave-uniform base + lane*16
  __builtin_amdgcn_global_load_lds((const __attribute__((address_space(1))) void*)g,
                                   (__attribute__((address_space(3))) void*)l, 16, 0, 0);
}

__device__ __forceinline__ f32x4 mfma16(s16x8 a, s16x8 b, f32x4 c) {
  return __builtin_amdgcn_mfma_f32_16x16x32_bf16(a, b, c, 0, 0, 0);
}

__device__ __forceinline__ f32x16 mfma32(s16x8 a, s16x8 b, f32x16 c) {
  return __builtin_amdgcn_mfma_f32_32x32x16_bf16(a, b, c, 0, 0, 0);
}

// XOR-swizzled LDS tile: logical (row, col8) stored at unit row*U + (col8 ^ (row&(U-1)))
__device__ __forceinline__ s16x8 lds_frag(const unsigned short* S, int row, int c8, int U) {
  int unit = row * U + (c8 ^ (row & (U - 1)));
  return *(const s16x8*)(S + unit * 8);
}

// ---------- fused preprocessing: cvt x->bf16 + both weight transposes ----------
// (passed r9). blocks [0,2048): cvt; [2048,5120): w_qkv T (96x32); [5120,6144): w_proj T.
__global__ __launch_bounds__(256) void prep(const float4* __restrict__ x4,
                                            unsigned short* __restrict__ Xb,
                                            const float* __restrict__ w_qkv,
                                            unsigned short* __restrict__ Wqt,
                                            const float* __restrict__ w_proj,
                                            unsigned short* __restrict__ Wpt) {
  __shared__ float tile[32][33];
  const int blk = blockIdx.x, t = threadIdx.x;
  if (blk < 2048) {
    // cvt_f32_bf16 body (grid-stride identical to the proven 2048x256 launch)
    const int n4 = 8388608 / 4, stride = 2048 * 256;
    for (int i = blk * 256 + t; i < n4; i += stride) {
      float4 v = x4[i];
      uint2 o;
      o.x = pk_bf16(v.x, v.y);
      o.y = pk_bf16(v.z, v.w);
      *(uint2*)(Xb + (size_t)i * 4) = o;
    }
    return;
  }
  // transpose_f32_bf16 body; thread (32,8) -> tx=t&31, ty=t>>5
  const float* in;
  unsigned short* out;
  int R, C, c0, r0;
  if (blk < 2048 + 3072) {
    int idx = blk - 2048;              // original grid (96, 32)
    in = w_qkv; out = Wqt; R = 1024; C = 3072;
    c0 = (idx % 96) * 32; r0 = (idx / 96) * 32;
  } else {
    int idx = blk - (2048 + 3072);     // original grid (32, 32)
    in = w_proj; out = Wpt; R = 1024; C = 1024;
    c0 = (idx & 31) * 32; r0 = (idx >> 5) * 32;
  }
  const int tx = t & 31, ty = t >> 5;
  #pragma unroll
  for (int i = 0; i < 32; i += 8)
    tile[ty + i][tx] = in[(size_t)(r0 + ty + i) * C + c0 + tx];
  __syncthreads();
  #pragma unroll
  for (int i = 0; i < 32; i += 8)
    out[(size_t)(c0 + ty + i) * R + r0 + tx] = bf16bits(tile[tx][ty + i]);
}

// V: [64 bh][2048][64] bf16 -> Vt: [64 bh][64][2048] bf16 (identity key order)
__global__ __launch_bounds__(256) void transpose_v(const unsigned short* __restrict__ V,
                                                   unsigned short* __restrict__ Vt) {
  __shared__ unsigned short sm[64 * 68];
  int bh = blockIdx.y, kt0 = blockIdx.x * 64;
  const unsigned short* v = V + (size_t)bh * 2048 * 64 + (size_t)kt0 * 64;  // 64x64 tile, contiguous
  unsigned short* vt = Vt + (size_t)bh * 64 * 2048;
  int t = threadIdx.x;
  #pragma unroll
  for (int i = 0; i < 4; ++i) {
    int u = i * 256 + t;        // uint2 index, 4 ushorts each
    int f = u * 4;              // flat = key*64 + d
    int k = f >> 6, d0 = f & 63;
    *(uint2*)&sm[k * 68 + d0] = *(const uint2*)&v[f];
  }
  __syncthreads();
  #pragma unroll
  for (int j = 0; j < 16; ++j) {
    int o = j * 256 + t;        // d*64 + k
    int d = o >> 6, k = o & 63;
    vt[(size_t)d * 2048 + kt0 + k] = sm[k * 68 + d];
  }
}

// ---------- GEMM: C[M,N] = A[M,K] @ Bt[N,K]^T, bf16 in, fp32 acc ----------
// r3-EXACT per-phase convoy schedule (3/3 passing: r2/r3/r9):
// BM=128, BN=256, BK=64, 512 thr (8 waves, 2M x 4N), per-wave 64x64.
// Triple-buffered LDS (144KB, 1 blk/CU). Per K-tile: 2 phases, each = {8
// ds_read (one kstep's a[4]+b[4]) || 3 global_load_lds chunks of tile t+2 ->
// s_barrier -> setprio(1) 16 MFMA setprio(0) -> s_barrier}. One counted
// s_waitcnt vmcnt(6) per tile, after the ph2 MFMA cluster.
//
// vmcnt ledger (6 loads/thread/tile, in-order retirement):
//   issue: ... (t-1).ph1:3 + (t-1).ph2:3 [tile t+1] | t.ph1:3 + t.ph2:3 [t+2]
//   at t.ph2 end: vmcnt(6) retires tile t+1 fully, leaves tile t+2's 6.
//   Per-wave count + 2 barriers before tile t+1's first ds_read = block-wide
//   certification (round-1 race rule). Prologue: 12 loads, vmcnt(6), barrier.
//   Tail: t+2>=NT -> vmcnt(0).

template <typename EPI>
__global__ __launch_bounds__(512, 2) void gemm8(const unsigned short* __restrict__ A,
                                                const unsigned short* __restrict__ Bt,
                                                int K, EPI epi) {
  __shared__ __align__(16) unsigned short As[3 * 128 * 64];  // 48KB, 3 slots
  __shared__ __align__(16) unsigned short Bs[3 * 256 * 64];  // 96KB, 3 slots
  const int tid = threadIdx.x, wid = tid >> 6, lane = tid & 63;
  const int quad = lane >> 4, l16 = lane & 15;
  const int bm0 = blockIdx.y * 128, bn0 = blockIdx.x * 256;
  const int wm = (wid & 1) * 64, wn = (wid >> 1) * 64;
  const int NT = K >> 6;
  f32x4 acc[4][4] = {};

  // staging (both-sides swizzle: linear LDS dest, inverse-swizzled global
  // source, swizzled ds_read — proven layout)
  const int srow = tid >> 3;
  const int sc8 = (tid & 7) ^ (srow & 7);
  // chunk k of K-tile tk into slot s: k 0..1 = A rows k*64.., k 2..5 = B rows (k-2)*64..
  auto stage = [&](int s, int tk, int k) {
    int col = tk * 64 + sc8 * 8;
    if (k < 2)
      async16(A + (size_t)(bm0 + k * 64 + srow) * K + col,
              (char*)As + s * 16384 + k * 8192 + wid * 1024);
    else
      async16(Bt + (size_t)(bn0 + (k - 2) * 64 + srow) * K + col,
              (char*)Bs + s * 32768 + (k - 2) * 8192 + wid * 1024);
  };

  // prologue: tiles 0 and 1 staged (12 loads); certify tile 0 block-wide
  #pragma unroll
  for (int k = 0; k < 6; ++k) stage(0, 0, k);
  #pragma unroll
  for (int k = 0; k < 6; ++k) stage(1, 1, k);
  asm volatile("s_waitcnt vmcnt(6)" ::: "memory");
  __builtin_amdgcn_s_barrier();
  __builtin_amdgcn_sched_barrier(0);

  int sc = 0;  // slot of tile t
  for (int t = 0; t < NT; ++t) {
    const unsigned short* as = As + sc * 8192;    // elements
    const unsigned short* bs = Bs + sc * 16384;   // elements
    const int sp = (sc == 0) ? 2 : sc - 1;        // slot (t+2)%3
    const bool pf = (t + 2 < NT);

    #pragma unroll
    for (int kk = 0; kk < 2; ++kk) {
      // phase body: ds_reads of this kstep + 3 staging chunks, then convoy
      s16x8 a[4], b[4];
      #pragma unroll
      for (int i = 0; i < 4; ++i) a[i] = lds_frag(as, wm + i * 16 + l16, kk * 4 + quad, 8);
      #pragma unroll
      for (int j = 0; j < 4; ++j) b[j] = lds_frag(bs, wn + j * 16 + l16, kk * 4 + quad, 8);
      if (pf) { stage(sp, t + 2, kk * 3 + 0); stage(sp, t + 2, kk * 3 + 1); stage(sp, t + 2, kk * 3 + 2); }
      __builtin_amdgcn_sched_barrier(0);  // pin phase memory ops before barrier
      __builtin_amdgcn_s_barrier();       // convoy: waves enter MFMA together
      __builtin_amdgcn_s_setprio(1);
      #pragma unroll
      for (int i = 0; i < 4; ++i)
        #pragma unroll
        for (int j = 0; j < 4; ++j)
          acc[i][j] = mfma16(a[i], b[j], acc[i][j]);
      __builtin_amdgcn_s_setprio(0);
      __builtin_amdgcn_sched_barrier(0);  // keep MFMA cluster inside the phase
      if (kk == 1) {                      // certify tile t+1 (counted, after MFMA)
        if (pf) asm volatile("s_waitcnt vmcnt(6)" ::: "memory");
        else    asm volatile("s_waitcnt vmcnt(0)" ::: "memory");
      }
      __builtin_amdgcn_s_barrier();       // phase end
    }
    sc = (sc == 2) ? 0 : sc + 1;
  }

  // epilogue: per (i,j) one call, 4 consecutive m per lane
  #pragma unroll
  for (int i = 0; i < 4; ++i)
    #pragma unroll
    for (int j = 0; j < 4; ++j)
      epi.store4(bm0 + wm + i * 16 + quad * 4, bn0 + wn + j * 16 + l16, acc[i][j]);
}

// QKV (swapped orientation): m = qkv-dim (s*1024 + h*64 + d), n = x-row (b*2048+ns).
// 4 consecutive m = 4 consecutive d -> one 8B store into [bh][ns][64] layout.
struct QKVEpi {
  unsigned short *Q, *K, *V;  // each [64 bh][2048 ns][64 d]
  float qscale;               // hd^-0.5 * log2(e): folds softmax into exp2 domain
  __device__ __forceinline__ void store4(int m0, int n, f32x4 v) const {
    int s = m0 >> 10, h = (m0 >> 6) & 15, d = m0 & 63;
    int b = n >> 11, ns = n & 2047;
    unsigned short* dst = (s == 0) ? Q : ((s == 1) ? K : V);
    float sc = (s == 0) ? qscale : 1.f;
    uint2 o;
    o.x = pk_bf16(v[0] * sc, v[1] * sc);
    o.y = pk_bf16(v[2] * sc, v[3] * sc);
    *(uint2*)&dst[(((size_t)b * 16 + h) * 2048 + ns) * 64 + d] = o;
  }
};

// Proj (swapped orientation): m = out-col, n = x-row. One float4 store + float4 bias.
struct ProjEpi {
  const float* bias;
  float* out;
  __device__ __forceinline__ void store4(int m0, int n, f32x4 v) const {
    float4 b4 = *(const float4*)&bias[m0];
    float4 o = {v[0] + b4.x, v[1] + b4.y, v[2] + b4.z, v[3] + b4.w};
    *(float4*)&out[(size_t)n * 1024 + m0] = o;
  }
};

// ---------- flash attention ----------
// SINGLE CHANGE THIS ROUND: the per-tile kf loop is split into
//   (1) QK^T for BOTH 32-key chunks -> st[0], st[1]   (two independent MFMA chains)
//   (2) softmax+pack+PV for chunk 0, then chunk 1
// Pure reordering of independent computations (identical ops, identical
// cross-lane mapping, identical barriers) to break the serial QK->SM->PV
// chain: the two QK chains interleave (hide MFMA latency), SM[0] VALU overlaps
// QK[1] tail, PV[0] MFMAs overlap SM[1] VALU. st[2] indexed only in unrolled
// loops (static indices). VGPR ~48 -> ~80, under the 128 budget @4 blk/CU.
// Everything else r9-exact: shuffle half-swap P path (6/6 passing), in-loop
// l_i reduce, fragment-major staging, XCD swizzle, setprio clusters.
// Q,K: [64 bh][2048][64] bf16 (Q pre-scaled by hd^-0.5*log2e);  Vt: [64 bh][64][2048]
// O: [4][2048][16][64] bf16.
__global__ __launch_bounds__(256, 4) void flash_attn(const unsigned short* __restrict__ Q,
                                                     const unsigned short* __restrict__ K,
                                                     const unsigned short* __restrict__ Vt,
                                                     unsigned short* __restrict__ O) {
  __shared__ __align__(16) unsigned short Ks[2][8 * 512];  // dbuf, 8 chunks (kf,s) of 64 frags
  __shared__ __align__(16) unsigned short Vs[2][8 * 512];  // dbuf, 8 chunks (ktstep,f)
  const int tid = threadIdx.x, wid = tid >> 6, lane = tid & 63;
  const int l31 = lane & 31, half = lane >> 5;
  // XCD swizzle: bijection bid -> (bh, qt); all blocks of a bh share bid&7
  const int bid = blockIdx.y * gridDim.x + blockIdx.x;  // 0..1023
  const int xcd = bid & 7, idx = bid >> 3;
  const int bh = xcd * 8 + (idx & 7);
  const int qt = idx >> 3;
  const unsigned short* Qg = Q + (size_t)bh * 2048 * 64;
  const unsigned short* Kg = K + (size_t)bh * 2048 * 64;
  const unsigned short* Vg = Vt + (size_t)bh * 64 * 2048;
  const int qrow = qt * 128 + wid * 32 + l31;  // this lane's q-row

  // Q as B-operand fragments: B[k=d][n=qrow]; lane holds d = s*16 + half*8 + j
  s16x8 qB[4];
  #pragma unroll
  for (int s = 0; s < 4; ++s)
    qB[s] = *(const s16x8*)&Qg[(size_t)qrow * 64 + s * 16 + half * 8];

  // staging: waves 0,1 stage K chunks 0..7 (kf=c>>2, s=c&3); waves 2,3 stage V
  // chunks 0..7 (ktstep=c>>1, f=c&1). Lane fetches exactly its fragment source.
  const bool isK = wid < 2;
  int sA[4];
  #pragma unroll
  for (int t = 0; t < 4; ++t) {
    int c = (wid & 1) * 4 + t;
    if (isK) sA[t] = ((c >> 2) * 32 + l31) * 64 + ((c & 3) * 2 + half) * 8;
    else     sA[t] = ((c & 1) * 32 + l31) * 2048 + (c >> 1) * 16 + half * 8;
  }

  auto stage = [&](int kt, int buf) {
    const int kb = kt * 64;
    #pragma unroll
    for (int t = 0; t < 4; ++t) {
      int c = (wid & 1) * 4 + t;
      if (isK) async16(Kg + (size_t)kb * 64 + sA[t], (char*)&Ks[buf][0] + c * 1024);
      else     async16(Vg + kb + sA[t],              (char*)&Vs[buf][0] + c * 1024);
    }
  };

  f32x16 oacc[2] = {};  // [f]: O^T[d = f*32 + (r&3)+8*(r>>2)+4*half][qrow]
  float l_i = 0.f;
  const f32x16 fz = {};

  stage(0, 0);
  for (int kt = 0; kt < 32; ++kt) {
    const int cur = kt & 1;
    __syncthreads();  // tile kt visible to all; buf cur^1 free (all done with kt-1)
    if (kt + 1 < 32) stage(kt + 1, cur ^ 1);  // in flight across this tile's compute
    const unsigned short* ks = &Ks[cur][0];
    const unsigned short* vs = &Vs[cur][0];

    // ---- (1) QK^T for both 32-key chunks: two independent MFMA chains ----
    f32x16 st[2];
    __builtin_amdgcn_s_setprio(1);
    #pragma unroll
    for (int kf = 0; kf < 2; ++kf) {
      // S^T = K @ Q^T; A-frag: keys kf*32 + (r&3)+8*(r>>2)+4*half, col = qrow
      {
        s16x8 a = *(const s16x8*)&ks[((kf * 4 + 0) * 64 + lane) * 8];
        st[kf] = mfma32(a, qB[0], fz);
      }
      #pragma unroll
      for (int s = 1; s < 4; ++s) {
        s16x8 a = *(const s16x8*)&ks[((kf * 4 + s) * 64 + lane) * 8];
        st[kf] = mfma32(a, qB[s], st[kf]);
      }
    }
    __builtin_amdgcn_s_setprio(0);

    // ---- (2) softmax + pack + PV per chunk (PV[0] MFMAs overlap SM[1]) ----
    #pragma unroll
    for (int kf = 0; kf < 2; ++kf) {
      // max-free softmax (scores bounded; fp32 can't overflow), tree-reduced sum
      float a0 = 0.f, a1 = 0.f, a2 = 0.f, a3 = 0.f;
      #pragma unroll
      for (int r = 0; r < 16; r += 4) {
        float p0 = __builtin_amdgcn_exp2f(st[kf][r + 0]);
        float p1 = __builtin_amdgcn_exp2f(st[kf][r + 1]);
        float p2 = __builtin_amdgcn_exp2f(st[kf][r + 2]);
        float p3 = __builtin_amdgcn_exp2f(st[kf][r + 3]);
        st[kf][r + 0] = p0; st[kf][r + 1] = p1; st[kf][r + 2] = p2; st[kf][r + 3] = p3;
        a0 += p0; a1 += p1; a2 += p2; a3 += p3;
      }
      float rs = (a0 + a1) + (a2 + a3);
      rs += __shfl_xor(rs, 32);
      l_i += rs;
      // pack P to bf16 B-frags (half-swap via dword shuffle) + PV
      #pragma unroll
      for (int t = 0; t < 2; ++t) {  // 16-key step within chunk
        int rb = t * 8;
        unsigned pa0 = pk_bf16(st[kf][rb + 0], st[kf][rb + 1]);
        unsigned pa1 = pk_bf16(st[kf][rb + 2], st[kf][rb + 3]);
        unsigned pb0 = pk_bf16(st[kf][rb + 4], st[kf][rb + 5]);
        unsigned pb1 = pk_bf16(st[kf][rb + 6], st[kf][rb + 7]);
        unsigned s0 = half ? pa0 : pb0;
        unsigned s1 = half ? pa1 : pb1;
        unsigned r0 = (unsigned)__shfl_xor((int)s0, 32);
        unsigned r1 = (unsigned)__shfl_xor((int)s1, 32);
        u32x4 bP;
        bP[0] = half ? r0 : pa0;  // B-frag keys kf*32 + t*16 + half*8 + {0..7}
        bP[1] = half ? r1 : pa1;
        bP[2] = half ? pb0 : r0;
        bP[3] = half ? pb1 : r1;
        __builtin_amdgcn_s_setprio(1);
        #pragma unroll
        for (int f = 0; f < 2; ++f) {
          s16x8 aV = *(const s16x8*)&vs[(((kf * 2 + t) * 2 + f) * 64 + lane) * 8];
          oacc[f] = mfma32(aV, __builtin_bit_cast(s16x8, bP), oacc[f]);
        }
        __builtin_amdgcn_s_setprio(0);
      }
    }
  }

  // epilogue: O^T D-layout -> O[b][ns][h][d]; regs q*4..q*4+3 are d contiguous
  const int b = bh >> 4, h = bh & 15;
  float inv = 1.f / l_i;
  size_t base = (((size_t)b * 2048 + qrow) * 16 + h) * 64;
  #pragma unroll
  for (int f = 0; f < 2; ++f)
    #pragma unroll
    for (int q = 0; q < 4; ++q) {
      int d0 = f * 32 + q * 8 + half * 4;
      uint2 o;
      o.x = pk_bf16(oacc[f][q * 4 + 0] * inv, oacc[f][q * 4 + 1] * inv);
      o.y = pk_bf16(oacc[f][q * 4 + 2] * inv, oacc[f][q * 4 + 3] * inv);
      *(uint2*)&O[base + d0] = o;
    }
}

// ---------- launch ----------

extern "C" void kernel_launch(void* const* d_in, const int* in_sizes, int n_in,
                              void* d_out, int out_size, void* d_ws, size_t ws_size,
                              hipStream_t stream) {
  (void)in_sizes; (void)n_in; (void)out_size; (void)ws_size;
  const float* x = (const float*)d_in[0];       // [4,2048,1024]
  const float* w_qkv = (const float*)d_in[1];   // [1024,3072]
  const float* w_proj = (const float*)d_in[2];  // [1024,1024]
  const float* b_proj = (const float*)d_in[3];  // [1024]
  float* out = (float*)d_out;
  char* ws = (char*)d_ws;
  const size_t MB = 1ull << 20;
  unsigned short* Xb  = (unsigned short*)(ws);            // 16MB (reused as Vt after QKV GEMM)
  unsigned short* Wqt = (unsigned short*)(ws + 16 * MB);  // 6MB  [3072][1024]
  unsigned short* Wpt = (unsigned short*)(ws + 22 * MB);  // 2MB  [1024][1024]
  unsigned short* Qb  = (unsigned short*)(ws + 24 * MB);  // 16MB [64 bh][2048][64]
  unsigned short* Kb  = (unsigned short*)(ws + 40 * MB);  // 16MB
  unsigned short* Vb  = (unsigned short*)(ws + 56 * MB);  // 16MB (reused as O after transpose_v)
  unsigned short* Vt  = Xb;  // Xb free after QKV GEMM
  unsigned short* Ob  = Vb;  // Vb free after transpose_v

  // fused: cvt + w_qkv transpose + w_proj transpose (one launch, 3 block ranges)
  prep<<<2048 + 3072 + 1024, 256, 0, stream>>>((const float4*)x, Xb, w_qkv, Wqt, w_proj, Wpt);

  // swapped orientation: A = weights (M=3072), Bt = X (N=8192); 32x24=768 blocks = 3 exact rounds
  QKVEpi e1{Qb, Kb, Vb, 0.125f * 1.44269504088896340736f};
  gemm8<QKVEpi><<<dim3(32, 24), 512, 0, stream>>>(Wqt, Xb, 1024, e1);

  transpose_v<<<dim3(32, 64), 256, 0, stream>>>(Vb, Vt);
  flash_attn<<<dim3(16, 64), 256, 0, stream>>>(Qb, Kb, Vt, Ob);

  // swapped orientation: A = W_proj^T (M=1024), Bt = attention output (N=8192); 256 blocks = 1 round
  ProjEpi e2{b_proj, out};
  gemm8<ProjEpi><<<dim3(32, 8), 512, 0, stream>>>(Wpt, Ob, 1024, e2);
}

// Round 11
// 271.190 us; speedup vs baseline: 1.1328x; 1.0278x over previous
//
#include <hip/hip_runtime.h>

typedef short s16x8 __attribute__((ext_vector_type(8)));
typedef float f32x4 __attribute__((ext_vector_type(4)));
typedef float f32x16 __attribute__((ext_vector_type(16)));
typedef unsigned u32x4 __attribute__((ext_vector_type(4)));

// ---------- helpers ----------

__device__ __forceinline__ unsigned short bf16bits(float f) {
  // round-to-nearest-even fp32 -> bf16 (finite inputs only)
  unsigned u = __builtin_bit_cast(unsigned, f);
  unsigned rnd = 0x7FFFu + ((u >> 16) & 1u);
  return (unsigned short)((u + rnd) >> 16);
}

__device__ __forceinline__ unsigned pk_bf16(float lo, float hi) {
  // dst[15:0]=bf16(lo), dst[31:16]=bf16(hi), RNE — one VALU op
  unsigned r;
  asm("v_cvt_pk_bf16_f32 %0, %1, %2" : "=v"(r) : "v"(lo), "v"(hi));
  return r;
}

__device__ __forceinline__ void async16(const void* g, void* l) {
  // global -> LDS direct copy, 16B per lane; LDS dest = wave-uniform base + lane*16
  __builtin_amdgcn_global_load_lds((const __attribute__((address_space(1))) void*)g,
                                   (__attribute__((address_space(3))) void*)l, 16, 0, 0);
}

__device__ __forceinline__ f32x4 mfma16(s16x8 a, s16x8 b, f32x4 c) {
  return __builtin_amdgcn_mfma_f32_16x16x32_bf16(a, b, c, 0, 0, 0);
}

__device__ __forceinline__ f32x16 mfma32(s16x8 a, s16x8 b, f32x16 c) {
  return __builtin_amdgcn_mfma_f32_32x32x16_bf16(a, b, c, 0, 0, 0);
}

// XOR-swizzled LDS tile: logical (row, col8) stored at unit row*U + (col8 ^ (row&(U-1)))
__device__ __forceinline__ s16x8 lds_frag(const unsigned short* S, int row, int c8, int U) {
  int unit = row * U + (c8 ^ (row & (U - 1)));
  return *(const s16x8*)(S + unit * 8);
}

// ---------- fused preprocessing: cvt x->bf16 + both weight transposes ----------
// (passed r9/r10). blocks [0,2048): cvt; [2048,5120): w_qkv T (96x32); [5120,6144): w_proj T.
__global__ __launch_bounds__(256) void prep(const float4* __restrict__ x4,
                                            unsigned short* __restrict__ Xb,
                                            const float* __restrict__ w_qkv,
                                            unsigned short* __restrict__ Wqt,
                                            const float* __restrict__ w_proj,
                                            unsigned short* __restrict__ Wpt) {
  __shared__ float tile[32][33];
  const int blk = blockIdx.x, t = threadIdx.x;
  if (blk < 2048) {
    // cvt_f32_bf16 body (grid-stride identical to the proven 2048x256 launch)
    const int n4 = 8388608 / 4, stride = 2048 * 256;
    for (int i = blk * 256 + t; i < n4; i += stride) {
      float4 v = x4[i];
      uint2 o;
      o.x = pk_bf16(v.x, v.y);
      o.y = pk_bf16(v.z, v.w);
      *(uint2*)(Xb + (size_t)i * 4) = o;
    }
    return;
  }
  // transpose_f32_bf16 body; thread (32,8) -> tx=t&31, ty=t>>5
  const float* in;
  unsigned short* out;
  int R, C, c0, r0;
  if (blk < 2048 + 3072) {
    int idx = blk - 2048;              // original grid (96, 32)
    in = w_qkv; out = Wqt; R = 1024; C = 3072;
    c0 = (idx % 96) * 32; r0 = (idx / 96) * 32;
  } else {
    int idx = blk - (2048 + 3072);     // original grid (32, 32)
    in = w_proj; out = Wpt; R = 1024; C = 1024;
    c0 = (idx & 31) * 32; r0 = (idx >> 5) * 32;
  }
  const int tx = t & 31, ty = t >> 5;
  #pragma unroll
  for (int i = 0; i < 32; i += 8)
    tile[ty + i][tx] = in[(size_t)(r0 + ty + i) * C + c0 + tx];
  __syncthreads();
  #pragma unroll
  for (int i = 0; i < 32; i += 8)
    out[(size_t)(c0 + ty + i) * R + r0 + tx] = bf16bits(tile[tx][ty + i]);
}

// V: [64 bh][2048][64] bf16 -> Vt: [64 bh][64][2048] bf16 (identity key order)
__global__ __launch_bounds__(256) void transpose_v(const unsigned short* __restrict__ V,
                                                   unsigned short* __restrict__ Vt) {
  __shared__ unsigned short sm[64 * 68];
  int bh = blockIdx.y, kt0 = blockIdx.x * 64;
  const unsigned short* v = V + (size_t)bh * 2048 * 64 + (size_t)kt0 * 64;  // 64x64 tile, contiguous
  unsigned short* vt = Vt + (size_t)bh * 64 * 2048;
  int t = threadIdx.x;
  #pragma unroll
  for (int i = 0; i < 4; ++i) {
    int u = i * 256 + t;        // uint2 index, 4 ushorts each
    int f = u * 4;              // flat = key*64 + d
    int k = f >> 6, d0 = f & 63;
    *(uint2*)&sm[k * 68 + d0] = *(const uint2*)&v[f];
  }
  __syncthreads();
  #pragma unroll
  for (int j = 0; j < 16; ++j) {
    int o = j * 256 + t;        // d*64 + k
    int d = o >> 6, k = o & 63;
    vt[(size_t)d * 2048 + kt0 + k] = sm[k * 68 + d];
  }
}

// ---------- GEMM: C[M,N] = A[M,K] @ Bt[N,K]^T, bf16 in, fp32 acc ----------
// r3-EXACT per-phase convoy schedule (4/4 passing: r2/r3/r9/r10):
// BM=128, BN=256, BK=64, 512 thr (8 waves, 2M x 4N), per-wave 64x64.
// Triple-buffered LDS (144KB, 1 blk/CU). Per K-tile: 2 phases, each = {8
// ds_read (one kstep's a[4]+b[4]) || 3 global_load_lds chunks of tile t+2 ->
// s_barrier -> setprio(1) 16 MFMA setprio(0) -> s_barrier}. One counted
// s_waitcnt vmcnt(6) per tile, after the ph2 MFMA cluster.
//
// vmcnt ledger (6 loads/thread/tile, in-order retirement):
//   issue: ... (t-1).ph1:3 + (t-1).ph2:3 [tile t+1] | t.ph1:3 + t.ph2:3 [t+2]
//   at t.ph2 end: vmcnt(6) retires tile t+1 fully, leaves tile t+2's 6.
//   Per-wave count + 2 barriers before tile t+1's first ds_read = block-wide
//   certification (round-1 race rule). Prologue: 12 loads, vmcnt(6), barrier.
//   Tail: t+2>=NT -> vmcnt(0).

template <typename EPI>
__global__ __launch_bounds__(512, 2) void gemm8(const unsigned short* __restrict__ A,
                                                const unsigned short* __restrict__ Bt,
                                                int K, EPI epi) {
  __shared__ __align__(16) unsigned short As[3 * 128 * 64];  // 48KB, 3 slots
  __shared__ __align__(16) unsigned short Bs[3 * 256 * 64];  // 96KB, 3 slots
  const int tid = threadIdx.x, wid = tid >> 6, lane = tid & 63;
  const int quad = lane >> 4, l16 = lane & 15;
  const int bm0 = blockIdx.y * 128, bn0 = blockIdx.x * 256;
  const int wm = (wid & 1) * 64, wn = (wid >> 1) * 64;
  const int NT = K >> 6;
  f32x4 acc[4][4] = {};

  // staging (both-sides swizzle: linear LDS dest, inverse-swizzled global
  // source, swizzled ds_read — proven layout)
  const int srow = tid >> 3;
  const int sc8 = (tid & 7) ^ (srow & 7);
  // chunk k of K-tile tk into slot s: k 0..1 = A rows k*64.., k 2..5 = B rows (k-2)*64..
  auto stage = [&](int s, int tk, int k) {
    int col = tk * 64 + sc8 * 8;
    if (k < 2)
      async16(A + (size_t)(bm0 + k * 64 + srow) * K + col,
              (char*)As + s * 16384 + k * 8192 + wid * 1024);
    else
      async16(Bt + (size_t)(bn0 + (k - 2) * 64 + srow) * K + col,
              (char*)Bs + s * 32768 + (k - 2) * 8192 + wid * 1024);
  };

  // prologue: tiles 0 and 1 staged (12 loads); certify tile 0 block-wide
  #pragma unroll
  for (int k = 0; k < 6; ++k) stage(0, 0, k);
  #pragma unroll
  for (int k = 0; k < 6; ++k) stage(1, 1, k);
  asm volatile("s_waitcnt vmcnt(6)" ::: "memory");
  __builtin_amdgcn_s_barrier();
  __builtin_amdgcn_sched_barrier(0);

  int sc = 0;  // slot of tile t
  for (int t = 0; t < NT; ++t) {
    const unsigned short* as = As + sc * 8192;    // elements
    const unsigned short* bs = Bs + sc * 16384;   // elements
    const int sp = (sc == 0) ? 2 : sc - 1;        // slot (t+2)%3
    const bool pf = (t + 2 < NT);

    #pragma unroll
    for (int kk = 0; kk < 2; ++kk) {
      // phase body: ds_reads of this kstep + 3 staging chunks, then convoy
      s16x8 a[4], b[4];
      #pragma unroll
      for (int i = 0; i < 4; ++i) a[i] = lds_frag(as, wm + i * 16 + l16, kk * 4 + quad, 8);
      #pragma unroll
      for (int j = 0; j < 4; ++j) b[j] = lds_frag(bs, wn + j * 16 + l16, kk * 4 + quad, 8);
      if (pf) { stage(sp, t + 2, kk * 3 + 0); stage(sp, t + 2, kk * 3 + 1); stage(sp, t + 2, kk * 3 + 2); }
      __builtin_amdgcn_sched_barrier(0);  // pin phase memory ops before barrier
      __builtin_amdgcn_s_barrier();       // convoy: waves enter MFMA together
      __builtin_amdgcn_s_setprio(1);
      #pragma unroll
      for (int i = 0; i < 4; ++i)
        #pragma unroll
        for (int j = 0; j < 4; ++j)
          acc[i][j] = mfma16(a[i], b[j], acc[i][j]);
      __builtin_amdgcn_s_setprio(0);
      __builtin_amdgcn_sched_barrier(0);  // keep MFMA cluster inside the phase
      if (kk == 1) {                      // certify tile t+1 (counted, after MFMA)
        if (pf) asm volatile("s_waitcnt vmcnt(6)" ::: "memory");
        else    asm volatile("s_waitcnt vmcnt(0)" ::: "memory");
      }
      __builtin_amdgcn_s_barrier();       // phase end
    }
    sc = (sc == 2) ? 0 : sc + 1;
  }

  // epilogue: per (i,j) one call, 4 consecutive m per lane
  #pragma unroll
  for (int i = 0; i < 4; ++i)
    #pragma unroll
    for (int j = 0; j < 4; ++j)
      epi.store4(bm0 + wm + i * 16 + quad * 4, bn0 + wn + j * 16 + l16, acc[i][j]);
}

// QKV (swapped orientation): m = qkv-dim (s*1024 + h*64 + d), n = x-row (b*2048+ns).
// 4 consecutive m = 4 consecutive d -> one 8B store into [bh][ns][64] layout.
struct QKVEpi {
  unsigned short *Q, *K, *V;  // each [64 bh][2048 ns][64 d]
  float qscale;               // hd^-0.5 * log2(e): folds softmax into exp2 domain
  __device__ __forceinline__ void store4(int m0, int n, f32x4 v) const {
    int s = m0 >> 10, h = (m0 >> 6) & 15, d = m0 & 63;
    int b = n >> 11, ns = n & 2047;
    unsigned short* dst = (s == 0) ? Q : ((s == 1) ? K : V);
    float sc = (s == 0) ? qscale : 1.f;
    uint2 o;
    o.x = pk_bf16(v[0] * sc, v[1] * sc);
    o.y = pk_bf16(v[2] * sc, v[3] * sc);
    *(uint2*)&dst[(((size_t)b * 16 + h) * 2048 + ns) * 64 + d] = o;
  }
};

// Proj (swapped orientation): m = out-col, n = x-row. One float4 store + float4 bias.
struct ProjEpi {
  const float* bias;
  float* out;
  __device__ __forceinline__ void store4(int m0, int n, f32x4 v) const {
    float4 b4 = *(const float4*)&bias[m0];
    float4 o = {v[0] + b4.x, v[1] + b4.y, v[2] + b4.z, v[3] + b4.w};
    *(float4*)&out[(size_t)n * 1024 + m0] = o;
  }
};

// ---------- flash attention ----------
// SINGLE CHANGE THIS ROUND: QBLK=64 per wave (two 32-q-row groups g=0,1).
// Mechanism: flash is LDS-pipe-top (58% est): each K/V fragment read served
// only 1 MFMA chain. Doubling q-rows per wave lets every K-frag feed TWO
// independent QK chains and every V-frag feed TWO PV MFMAs -> LDS reads per
// FLOP halve. Grid 1024 -> 512 blocks (= 2/CU exact); LDS/block unchanged;
// launch_bounds(256,2) for the 256-VGPR budget (est ~170, no spill).
// Per-g code is byte-identical to the 6/6-proven shuffle path; staging,
// barriers, XCD swizzle decomposition (512 = 8 xcd x 8 bh x 8 qt) unchanged
// in structure.
// Q,K: [64 bh][2048][64] bf16 (Q pre-scaled by hd^-0.5*log2e);  Vt: [64 bh][64][2048]
// O: [4][2048][16][64] bf16.
__global__ __launch_bounds__(256, 2) void flash_attn(const unsigned short* __restrict__ Q,
                                                     const unsigned short* __restrict__ K,
                                                     const unsigned short* __restrict__ Vt,
                                                     unsigned short* __restrict__ O) {
  __shared__ __align__(16) unsigned short Ks[2][8 * 512];  // dbuf, 8 chunks (kf,s) of 64 frags
  __shared__ __align__(16) unsigned short Vs[2][8 * 512];  // dbuf, 8 chunks (ktstep,f)
  const int tid = threadIdx.x, wid = tid >> 6, lane = tid & 63;
  const int l31 = lane & 31, half = lane >> 5;
  // XCD swizzle: bijection bid -> (bh, qt); all blocks of a bh share bid&7
  const int bid = blockIdx.y * gridDim.x + blockIdx.x;  // 0..511
  const int xcd = bid & 7, idx = bid >> 3;
  const int bh = xcd * 8 + (idx & 7);
  const int qt = idx >> 3;                              // 0..7 (256 q-rows per block)
  const unsigned short* Qg = Q + (size_t)bh * 2048 * 64;
  const unsigned short* Kg = K + (size_t)bh * 2048 * 64;
  const unsigned short* Vg = Vt + (size_t)bh * 64 * 2048;
  // this lane's two q-rows: g=0,1
  const int qrow0 = qt * 256 + wid * 64 + l31;
  const int qrow1 = qrow0 + 32;

  // Q as B-operand fragments per group: B[k=d][n=qrow]; lane holds d = s*16 + half*8 + j
  s16x8 qB[2][4];
  #pragma unroll
  for (int s = 0; s < 4; ++s) {
    qB[0][s] = *(const s16x8*)&Qg[(size_t)qrow0 * 64 + s * 16 + half * 8];
    qB[1][s] = *(const s16x8*)&Qg[(size_t)qrow1 * 64 + s * 16 + half * 8];
  }

  // staging: waves 0,1 stage K chunks 0..7 (kf=c>>2, s=c&3); waves 2,3 stage V
  // chunks 0..7 (ktstep=c>>1, f=c&1). Lane fetches exactly its fragment source.
  const bool isK = wid < 2;
  int sA[4];
  #pragma unroll
  for (int t = 0; t < 4; ++t) {
    int c = (wid & 1) * 4 + t;
    if (isK) sA[t] = ((c >> 2) * 32 + l31) * 64 + ((c & 3) * 2 + half) * 8;
    else     sA[t] = ((c & 1) * 32 + l31) * 2048 + (c >> 1) * 16 + half * 8;
  }

  auto stage = [&](int kt, int buf) {
    const int kb = kt * 64;
    #pragma unroll
    for (int t = 0; t < 4; ++t) {
      int c = (wid & 1) * 4 + t;
      if (isK) async16(Kg + (size_t)kb * 64 + sA[t], (char*)&Ks[buf][0] + c * 1024);
      else     async16(Vg + kb + sA[t],              (char*)&Vs[buf][0] + c * 1024);
    }
  };

  f32x16 oacc[2][2] = {};  // [g][f]: O^T[d = f*32 + (r&3)+8*(r>>2)+4*half][qrow_g]
  float l_i[2] = {0.f, 0.f};
  const f32x16 fz = {};

  stage(0, 0);
  for (int kt = 0; kt < 32; ++kt) {
    const int cur = kt & 1;
    __syncthreads();  // tile kt visible to all; buf cur^1 free (all done with kt-1)
    if (kt + 1 < 32) stage(kt + 1, cur ^ 1);  // in flight across this tile's compute
    const unsigned short* ks = &Ks[cur][0];
    const unsigned short* vs = &Vs[cur][0];

    #pragma unroll
    for (int kf = 0; kf < 2; ++kf) {  // 32-key chunk: QK -> softmax -> PV
      // S^T = K @ Q^T; A-frag: keys kf*32 + (r&3)+8*(r>>2)+4*half, col = qrow_g.
      // K-frags read ONCE, feed both q-groups' chains (the LDS saving).
      f32x16 st[2];
      __builtin_amdgcn_s_setprio(1);
      {
        s16x8 a = *(const s16x8*)&ks[((kf * 4 + 0) * 64 + lane) * 8];
        st[0] = mfma32(a, qB[0][0], fz);
        st[1] = mfma32(a, qB[1][0], fz);
      }
      #pragma unroll
      for (int s = 1; s < 4; ++s) {
        s16x8 a = *(const s16x8*)&ks[((kf * 4 + s) * 64 + lane) * 8];
        st[0] = mfma32(a, qB[0][s], st[0]);
        st[1] = mfma32(a, qB[1][s], st[1]);
      }
      __builtin_amdgcn_s_setprio(0);
      // max-free softmax per group (scores bounded; fp32 can't overflow)
      #pragma unroll
      for (int g = 0; g < 2; ++g) {
        float a0 = 0.f, a1 = 0.f, a2 = 0.f, a3 = 0.f;
        #pragma unroll
        for (int r = 0; r < 16; r += 4) {
          float p0 = __builtin_amdgcn_exp2f(st[g][r + 0]);
          float p1 = __builtin_amdgcn_exp2f(st[g][r + 1]);
          float p2 = __builtin_amdgcn_exp2f(st[g][r + 2]);
          float p3 = __builtin_amdgcn_exp2f(st[g][r + 3]);
          st[g][r + 0] = p0; st[g][r + 1] = p1; st[g][r + 2] = p2; st[g][r + 3] = p3;
          a0 += p0; a1 += p1; a2 += p2; a3 += p3;
        }
        float rs = (a0 + a1) + (a2 + a3);
        rs += __shfl_xor(rs, 32);
        l_i[g] += rs;
      }
      // pack P per group (half-swap via dword shuffle, proven path) + shared-V PV
      #pragma unroll
      for (int t = 0; t < 2; ++t) {  // 16-key step within chunk
        int rb = t * 8;
        u32x4 bP[2];
        #pragma unroll
        for (int g = 0; g < 2; ++g) {
          unsigned pa0 = pk_bf16(st[g][rb + 0], st[g][rb + 1]);
          unsigned pa1 = pk_bf16(st[g][rb + 2], st[g][rb + 3]);
          unsigned pb0 = pk_bf16(st[g][rb + 4], st[g][rb + 5]);
          unsigned pb1 = pk_bf16(st[g][rb + 6], st[g][rb + 7]);
          unsigned s0 = half ? pa0 : pb0;
          unsigned s1 = half ? pa1 : pb1;
          unsigned r0 = (unsigned)__shfl_xor((int)s0, 32);
          unsigned r1 = (unsigned)__shfl_xor((int)s1, 32);
          bP[g][0] = half ? r0 : pa0;  // B-frag keys kf*32 + t*16 + half*8 + {0..7}
          bP[g][1] = half ? r1 : pa1;
          bP[g][2] = half ? pb0 : r0;
          bP[g][3] = half ? pb1 : r1;
        }
        __builtin_amdgcn_s_setprio(1);
        #pragma unroll
        for (int f = 0; f < 2; ++f) {
          // V-frag read ONCE, feeds both q-groups (the LDS saving)
          s16x8 aV = *(const s16x8*)&vs[(((kf * 2 + t) * 2 + f) * 64 + lane) * 8];
          oacc[0][f] = mfma32(aV, __builtin_bit_cast(s16x8, bP[0]), oacc[0][f]);
          oacc[1][f] = mfma32(aV, __builtin_bit_cast(s16x8, bP[1]), oacc[1][f]);
        }
        __builtin_amdgcn_s_setprio(0);
      }
    }
  }

  // epilogue: O^T D-layout -> O[b][ns][h][d]; regs q*4..q*4+3 are d contiguous
  const int b = bh >> 4, h = bh & 15;
  #pragma unroll
  for (int g = 0; g < 2; ++g) {
    float inv = 1.f / l_i[g];
    int qrow = g ? qrow1 : qrow0;
    size_t base = (((size_t)b * 2048 + qrow) * 16 + h) * 64;
    #pragma unroll
    for (int f = 0; f < 2; ++f)
      #pragma unroll
      for (int q = 0; q < 4; ++q) {
        int d0 = f * 32 + q * 8 + half * 4;
        uint2 o;
        o.x = pk_bf16(oacc[g][f][q * 4 + 0] * inv, oacc[g][f][q * 4 + 1] * inv);
        o.y = pk_bf16(oacc[g][f][q * 4 + 2] * inv, oacc[g][f][q * 4 + 3] * inv);
        *(uint2*)&O[base + d0] = o;
      }
  }
}

// ---------- launch ----------

extern "C" void kernel_launch(void* const* d_in, const int* in_sizes, int n_in,
                              void* d_out, int out_size, void* d_ws, size_t ws_size,
                              hipStream_t stream) {
  (void)in_sizes; (void)n_in; (void)out_size; (void)ws_size;
  const float* x = (const float*)d_in[0];       // [4,2048,1024]
  const float* w_qkv = (const float*)d_in[1];   // [1024,3072]
  const float* w_proj = (const float*)d_in[2];  // [1024,1024]
  const float* b_proj = (const float*)d_in[3];  // [1024]
  float* out = (float*)d_out;
  char* ws = (char*)d_ws;
  const size_t MB = 1ull << 20;
  unsigned short* Xb  = (unsigned short*)(ws);            // 16MB (reused as Vt after QKV GEMM)
  unsigned short* Wqt = (unsigned short*)(ws + 16 * MB);  // 6MB  [3072][1024]
  unsigned short* Wpt = (unsigned short*)(ws + 22 * MB);  // 2MB  [1024][1024]
  unsigned short* Qb  = (unsigned short*)(ws + 24 * MB);  // 16MB [64 bh][2048][64]
  unsigned short* Kb  = (unsigned short*)(ws + 40 * MB);  // 16MB
  unsigned short* Vb  = (unsigned short*)(ws + 56 * MB);  // 16MB (reused as O after transpose_v)
  unsigned short* Vt  = Xb;  // Xb free after QKV GEMM
  unsigned short* Ob  = Vb;  // Vb free after transpose_v

  // fused: cvt + w_qkv transpose + w_proj transpose (one launch, 3 block ranges)
  prep<<<2048 + 3072 + 1024, 256, 0, stream>>>((const float4*)x, Xb, w_qkv, Wqt, w_proj, Wpt);

  // swapped orientation: A = weights (M=3072), Bt = X (N=8192); 32x24=768 blocks = 3 exact rounds
  QKVEpi e1{Qb, Kb, Vb, 0.125f * 1.44269504088896340736f};
  gemm8<QKVEpi><<<dim3(32, 24), 512, 0, stream>>>(Wqt, Xb, 1024, e1);

  transpose_v<<<dim3(32, 64), 256, 0, stream>>>(Vb, Vt);
  // QBLK=64 flash: 8 q-tiles x 64 bh = 512 blocks = 2/CU exact
  flash_attn<<<dim3(8, 64), 256, 0, stream>>>(Qb, Kb, Vt, Ob);

  // swapped orientation: A = W_proj^T (M=1024), Bt = attention output (N=8192); 256 blocks = 1 round
  ProjEpi e2{b_proj, out};
  gemm8<ProjEpi><<<dim3(32, 8), 512, 0, stream>>>(Wpt, Ob, 1024, e2);
}